// Round 1
// baseline (56.895 us; speedup 1.0000x reference)
//
#include <hip/hip_runtime.h>
#include <math.h>

// Problem constants
#define BATCH   8
#define LDIM    20
#define PIX     25600   // 160*160
#define PIX4    6400    // PIX/4
#define NLPAIRS 400     // N*L
#define NLR     800     // N*L*2

#define CHUNKS    4
#define CHUNK_NLR 200   // NLR / CHUNKS (must keep (r=0,r=1) pairs together: 200 % 2 == 0)

// ---------------------------------------------------------------------------
// Kernel A: projection + rotation.
// One block per (n,l) pair. Streams basis rows (nl*2) and (nl*2+1) once,
// dots against all 8 batch images (x is L2-resident), reduces, applies the
// complex rotation in the epilogue, writes rot[nlr][b] to workspace.
// ---------------------------------------------------------------------------
__global__ __launch_bounds__(256) void proj_rot_kernel(
    const float* __restrict__ x,       // [8][25600]
    const float* __restrict__ basis,   // [800][25600]
    const float* __restrict__ angles,  // [8]
    float* __restrict__ rot)           // [800][8]
{
    const int nl  = blockIdx.x;         // 0..399
    const int l   = nl % LDIM;
    const int tid = threadIdx.x;

    const float4* __restrict__ b0p = (const float4*)(basis + (size_t)(nl * 2 + 0) * PIX);
    const float4* __restrict__ b1p = (const float4*)(basis + (size_t)(nl * 2 + 1) * PIX);
    const float4* __restrict__ x4  = (const float4*)x;

    float acc0[BATCH], acc1[BATCH];
    #pragma unroll
    for (int b = 0; b < BATCH; ++b) { acc0[b] = 0.0f; acc1[b] = 0.0f; }

    // PIX4 = 6400 = 25 * 256 exactly
    for (int i = tid; i < PIX4; i += 256) {
        float4 bv0 = b0p[i];
        float4 bv1 = b1p[i];
        #pragma unroll
        for (int b = 0; b < BATCH; ++b) {
            float4 xv = x4[(size_t)b * PIX4 + i];
            acc0[b] = fmaf(bv0.x, xv.x, acc0[b]);
            acc0[b] = fmaf(bv0.y, xv.y, acc0[b]);
            acc0[b] = fmaf(bv0.z, xv.z, acc0[b]);
            acc0[b] = fmaf(bv0.w, xv.w, acc0[b]);
            acc1[b] = fmaf(bv1.x, xv.x, acc1[b]);
            acc1[b] = fmaf(bv1.y, xv.y, acc1[b]);
            acc1[b] = fmaf(bv1.z, xv.z, acc1[b]);
            acc1[b] = fmaf(bv1.w, xv.w, acc1[b]);
        }
    }

    // Wave-level reduction (64 lanes)
    #pragma unroll
    for (int b = 0; b < BATCH; ++b) {
        #pragma unroll
        for (int off = 32; off > 0; off >>= 1) {
            acc0[b] += __shfl_down(acc0[b], off);
            acc1[b] += __shfl_down(acc1[b], off);
        }
    }

    __shared__ float red[4][16];
    const int wave = tid >> 6;
    const int lane = tid & 63;
    if (lane == 0) {
        #pragma unroll
        for (int b = 0; b < BATCH; ++b) {
            red[wave][b]     = acc0[b];
            red[wave][8 + b] = acc1[b];
        }
    }
    __syncthreads();

    if (tid < BATCH) {
        const int b = tid;
        float c0 = red[0][b] + red[1][b] + red[2][b] + red[3][b];
        float c1 = red[0][8 + b] + red[1][8 + b] + red[2][8 + b] + red[3][8 + b];
        float ang = angles[b] * (float)l;
        float ca = cosf(ang);
        float sa = sinf(ang);
        // a = c0*ca + c1*sa ; b = c1*ca - c0*sa
        rot[(size_t)(nl * 2 + 0) * BATCH + b] = fmaf(c0, ca, c1 * sa);
        rot[(size_t)(nl * 2 + 1) * BATCH + b] = fmaf(c1, ca, -c0 * sa);
    }
}

// ---------------------------------------------------------------------------
// Kernel B: reconstruction.
// grid = (100 pixel tiles of 256, 4 nlr chunks of 200). Each block stages its
// rot chunk in LDS (broadcast reads), streams its basis slice exactly once,
// and atomicAdds 8 partial outputs per thread into pre-zeroed d_out.
// ---------------------------------------------------------------------------
__global__ __launch_bounds__(256) void recon_kernel(
    const float* __restrict__ basis,   // [800][25600]
    const float* __restrict__ rot,     // [800][8]
    float* __restrict__ out)           // [8][25600]
{
    __shared__ float rl[CHUNK_NLR * BATCH];   // 6.4 KB

    const int tid = threadIdx.x;
    const int c0  = blockIdx.y * CHUNK_NLR;

    for (int p = tid; p < CHUNK_NLR * BATCH; p += 256)
        rl[p] = rot[(size_t)c0 * BATCH + p];
    __syncthreads();

    const int pix = blockIdx.x * 256 + tid;   // 100*256 = 25600 exactly

    float acc[BATCH];
    #pragma unroll
    for (int b = 0; b < BATCH; ++b) acc[b] = 0.0f;

    const float* __restrict__ bp = basis + (size_t)c0 * PIX + pix;

    #pragma unroll 4
    for (int k = 0; k < CHUNK_NLR; ++k) {
        float bv = bp[(size_t)k * PIX];
        float4 r0 = *(const float4*)&rl[k * BATCH];
        float4 r1 = *(const float4*)&rl[k * BATCH + 4];
        acc[0] = fmaf(bv, r0.x, acc[0]);
        acc[1] = fmaf(bv, r0.y, acc[1]);
        acc[2] = fmaf(bv, r0.z, acc[2]);
        acc[3] = fmaf(bv, r0.w, acc[3]);
        acc[4] = fmaf(bv, r1.x, acc[4]);
        acc[5] = fmaf(bv, r1.y, acc[5]);
        acc[6] = fmaf(bv, r1.z, acc[6]);
        acc[7] = fmaf(bv, r1.w, acc[7]);
    }

    #pragma unroll
    for (int b = 0; b < BATCH; ++b)
        atomicAdd(&out[(size_t)b * PIX + pix], acc[b]);
}

extern "C" void kernel_launch(void* const* d_in, const int* in_sizes, int n_in,
                              void* d_out, int out_size, void* d_ws, size_t ws_size,
                              hipStream_t stream) {
    (void)in_sizes; (void)n_in; (void)ws_size;

    const float* x      = (const float*)d_in[0];   // [8][1][160][160]
    const float* basis  = (const float*)d_in[1];   // [20][20][2][160][160]
    const float* angles = (const float*)d_in[2];   // [8]
    float* out = (float*)d_out;                    // [8][1][160][160]
    float* rot = (float*)d_ws;                     // [800][8] = 25.6 KB

    // d_out is poisoned by the harness; zero it for the atomic accumulation.
    hipMemsetAsync(d_out, 0, (size_t)out_size * sizeof(float), stream);

    proj_rot_kernel<<<dim3(NLPAIRS), dim3(256), 0, stream>>>(x, basis, angles, rot);
    recon_kernel<<<dim3(PIX / 256, CHUNKS), dim3(256), 0, stream>>>(basis, rot, out);
}

// Round 2
// 45.615 us; speedup vs baseline: 1.2473x; 1.2473x over previous
//
#include <hip/hip_runtime.h>
#include <math.h>

// Problem constants
#define BATCH   8
#define LDIM    20
#define PIX     25600   // 160*160
#define PIX4    6400    // PIX/4 (float4 elements per image)
#define NLPAIRS 400     // N*L
#define NLR     800     // N*L*2

// Projection split
#define NLG     2                   // nl-pairs per block (4 basis rows)
#define KSPLIT  5                   // pixel-dimension split
#define SLICE   (PIX4 / KSPLIT)     // 1280 float4 = 5 iters * 256 threads

// Reconstruction split
#define CHUNKS    8
#define CHUNK_NLR 100               // NLR / CHUNKS (keeps (r0,r1) pairs together)

// ---------------------------------------------------------------------------
// Kernel A: split-K projection.
// grid = (200 nl-groups, 5 K-slices). Each block handles 4 basis rows over a
// 1280-float4 pixel slice, reduces 32 partials, atomicAdds into coeffs[800][8].
// ---------------------------------------------------------------------------
__global__ __launch_bounds__(256) void proj_kernel(
    const float* __restrict__ x,       // [8][25600]
    const float* __restrict__ basis,   // [800][25600]
    float* __restrict__ coeffs)        // [800][8], pre-zeroed
{
    const int tid   = threadIdx.x;
    const int rbase = blockIdx.x * (NLG * 2);        // first basis row (4 rows)
    const int kbase = blockIdx.y * SLICE;            // float4 offset of slice

    const float4* __restrict__ r0 = (const float4*)(basis + (size_t)(rbase + 0) * PIX);
    const float4* __restrict__ r1 = (const float4*)(basis + (size_t)(rbase + 1) * PIX);
    const float4* __restrict__ r2 = (const float4*)(basis + (size_t)(rbase + 2) * PIX);
    const float4* __restrict__ r3 = (const float4*)(basis + (size_t)(rbase + 3) * PIX);
    const float4* __restrict__ x4 = (const float4*)x;

    float acc[4][BATCH];
    #pragma unroll
    for (int r = 0; r < 4; ++r)
        #pragma unroll
        for (int b = 0; b < BATCH; ++b) acc[r][b] = 0.0f;

    #pragma unroll
    for (int it = 0; it < SLICE / 256; ++it) {
        const int i = kbase + it * 256 + tid;
        float4 b0 = r0[i];
        float4 b1 = r1[i];
        float4 b2 = r2[i];
        float4 b3 = r3[i];
        #pragma unroll
        for (int b = 0; b < BATCH; ++b) {
            float4 xv = x4[(size_t)b * PIX4 + i];
            acc[0][b] = fmaf(b0.x, xv.x, acc[0][b]);
            acc[0][b] = fmaf(b0.y, xv.y, acc[0][b]);
            acc[0][b] = fmaf(b0.z, xv.z, acc[0][b]);
            acc[0][b] = fmaf(b0.w, xv.w, acc[0][b]);
            acc[1][b] = fmaf(b1.x, xv.x, acc[1][b]);
            acc[1][b] = fmaf(b1.y, xv.y, acc[1][b]);
            acc[1][b] = fmaf(b1.z, xv.z, acc[1][b]);
            acc[1][b] = fmaf(b1.w, xv.w, acc[1][b]);
            acc[2][b] = fmaf(b2.x, xv.x, acc[2][b]);
            acc[2][b] = fmaf(b2.y, xv.y, acc[2][b]);
            acc[2][b] = fmaf(b2.z, xv.z, acc[2][b]);
            acc[2][b] = fmaf(b2.w, xv.w, acc[2][b]);
            acc[3][b] = fmaf(b3.x, xv.x, acc[3][b]);
            acc[3][b] = fmaf(b3.y, xv.y, acc[3][b]);
            acc[3][b] = fmaf(b3.z, xv.z, acc[3][b]);
            acc[3][b] = fmaf(b3.w, xv.w, acc[3][b]);
        }
    }

    // Intra-wave butterfly reduction of all 32 partials
    #pragma unroll
    for (int r = 0; r < 4; ++r)
        #pragma unroll
        for (int b = 0; b < BATCH; ++b)
            #pragma unroll
            for (int off = 32; off > 0; off >>= 1)
                acc[r][b] += __shfl_down(acc[r][b], off);

    __shared__ float red[4][32];
    const int wave = tid >> 6;
    const int lane = tid & 63;
    if (lane == 0) {
        #pragma unroll
        for (int r = 0; r < 4; ++r)
            #pragma unroll
            for (int b = 0; b < BATCH; ++b)
                red[wave][r * BATCH + b] = acc[r][b];
    }
    __syncthreads();

    if (tid < 32) {
        const int r = tid >> 3;   // row 0..3
        const int b = tid & 7;    // batch
        float v = red[0][tid] + red[1][tid] + red[2][tid] + red[3][tid];
        atomicAdd(&coeffs[(size_t)(rbase + r) * BATCH + b], v);
    }
}

// ---------------------------------------------------------------------------
// Kernel B: rotation (fused into LDS staging) + reconstruction.
// grid = (100 pixel tiles, 8 nlr chunks). Stages the rotated coeff chunk in
// LDS, streams its basis slice once, atomicAdds into pre-zeroed d_out.
// ---------------------------------------------------------------------------
__global__ __launch_bounds__(256) void recon_kernel(
    const float* __restrict__ basis,   // [800][25600]
    const float* __restrict__ coeffs,  // [800][8] (unrotated)
    const float* __restrict__ angles,  // [8]
    float* __restrict__ out)           // [8][25600]
{
    __shared__ float rl[CHUNK_NLR * BATCH];   // 3.2 KB

    const int tid = threadIdx.x;
    const int c0  = blockIdx.y * CHUNK_NLR;

    // Stage + rotate: a = c0*ca + c1*sa ; b = c1*ca - c0*sa
    for (int idx = tid; idx < CHUNK_NLR * BATCH; idx += 256) {
        const int k   = idx >> 3;           // nlr within chunk
        const int b   = idx & 7;            // batch
        const int nlr = c0 + k;
        const int r   = nlr & 1;
        const int l   = (nlr >> 1) % LDIM;
        float self  = coeffs[(size_t)nlr * BATCH + b];
        float other = coeffs[(size_t)(nlr ^ 1) * BATCH + b];
        float ang = angles[b] * (float)l;
        float ca, sa;
        __sincosf(ang, &sa, &ca);
        rl[idx] = r == 0 ? fmaf(self, ca, other * sa)
                         : fmaf(self, ca, -other * sa);
    }
    __syncthreads();

    const int pix = blockIdx.x * 256 + tid;   // 100*256 = 25600 exactly

    float acc[BATCH];
    #pragma unroll
    for (int b = 0; b < BATCH; ++b) acc[b] = 0.0f;

    const float* __restrict__ bp = basis + (size_t)c0 * PIX + pix;

    #pragma unroll 5
    for (int k = 0; k < CHUNK_NLR; ++k) {
        float bv = bp[(size_t)k * PIX];
        float4 v0 = *(const float4*)&rl[k * BATCH];
        float4 v1 = *(const float4*)&rl[k * BATCH + 4];
        acc[0] = fmaf(bv, v0.x, acc[0]);
        acc[1] = fmaf(bv, v0.y, acc[1]);
        acc[2] = fmaf(bv, v0.z, acc[2]);
        acc[3] = fmaf(bv, v0.w, acc[3]);
        acc[4] = fmaf(bv, v1.x, acc[4]);
        acc[5] = fmaf(bv, v1.y, acc[5]);
        acc[6] = fmaf(bv, v1.z, acc[6]);
        acc[7] = fmaf(bv, v1.w, acc[7]);
    }

    #pragma unroll
    for (int b = 0; b < BATCH; ++b)
        atomicAdd(&out[(size_t)b * PIX + pix], acc[b]);
}

extern "C" void kernel_launch(void* const* d_in, const int* in_sizes, int n_in,
                              void* d_out, int out_size, void* d_ws, size_t ws_size,
                              hipStream_t stream) {
    (void)in_sizes; (void)n_in; (void)ws_size;

    const float* x      = (const float*)d_in[0];   // [8][1][160][160]
    const float* basis  = (const float*)d_in[1];   // [20][20][2][160][160]
    const float* angles = (const float*)d_in[2];   // [8]
    float* out    = (float*)d_out;                 // [8][1][160][160]
    float* coeffs = (float*)d_ws;                  // [800][8] = 25.6 KB

    // Zero accumulation targets (harness poisons them).
    hipMemsetAsync(d_ws, 0, (size_t)NLR * BATCH * sizeof(float), stream);
    hipMemsetAsync(d_out, 0, (size_t)out_size * sizeof(float), stream);

    proj_kernel<<<dim3(NLPAIRS / NLG, KSPLIT), dim3(256), 0, stream>>>(x, basis, coeffs);
    recon_kernel<<<dim3(PIX / 256, CHUNKS), dim3(256), 0, stream>>>(basis, coeffs, angles, out);
}

// Round 3
// 42.124 us; speedup vs baseline: 1.3507x; 1.0829x over previous
//
#include <hip/hip_runtime.h>
#include <math.h>

// Problem constants
#define BATCH   8
#define LDIM    20
#define PIX     25600   // 160*160
#define PIX4    6400    // PIX/4 (float4 elements per image)
#define NLPAIRS 400     // N*L
#define NLR     800     // N*L*2

// Projection split
#define NLG     2                   // nl-pairs per block (4 basis rows)
#define KSPLIT  5                   // pixel-dimension split
#define SLICE   (PIX4 / KSPLIT)     // 1280 float4 = 5 iters * 256 threads

// Reconstruction split
#define RPIX    64                  // pixels per recon block
#define RKS     4                   // k-slices (one per wave)
#define RKLEN   (NLR / RKS)         // 200 k per wave

// ---------------------------------------------------------------------------
// Kernel A: split-K projection, no atomics.
// grid = (200 nl-groups, 5 K-slices). Each block handles 4 basis rows over a
// 1280-float4 pixel slice, reduces 32 partials, writes them to
// part[slice][800][8] (workspace). No memset needed.
// ---------------------------------------------------------------------------
__global__ __launch_bounds__(256) void proj_kernel(
    const float* __restrict__ x,       // [8][25600]
    const float* __restrict__ basis,   // [800][25600]
    float* __restrict__ part)          // [KSPLIT][800][8]
{
    const int tid   = threadIdx.x;
    const int rbase = blockIdx.x * (NLG * 2);        // first basis row (4 rows)
    const int kbase = blockIdx.y * SLICE;            // float4 offset of slice

    const float4* __restrict__ r0 = (const float4*)(basis + (size_t)(rbase + 0) * PIX);
    const float4* __restrict__ r1 = (const float4*)(basis + (size_t)(rbase + 1) * PIX);
    const float4* __restrict__ r2 = (const float4*)(basis + (size_t)(rbase + 2) * PIX);
    const float4* __restrict__ r3 = (const float4*)(basis + (size_t)(rbase + 3) * PIX);
    const float4* __restrict__ x4 = (const float4*)x;

    float acc[4][BATCH];
    #pragma unroll
    for (int r = 0; r < 4; ++r)
        #pragma unroll
        for (int b = 0; b < BATCH; ++b) acc[r][b] = 0.0f;

    #pragma unroll
    for (int it = 0; it < SLICE / 256; ++it) {
        const int i = kbase + it * 256 + tid;
        float4 b0 = r0[i];
        float4 b1 = r1[i];
        float4 b2 = r2[i];
        float4 b3 = r3[i];
        #pragma unroll
        for (int b = 0; b < BATCH; ++b) {
            float4 xv = x4[(size_t)b * PIX4 + i];
            acc[0][b] = fmaf(b0.x, xv.x, acc[0][b]);
            acc[0][b] = fmaf(b0.y, xv.y, acc[0][b]);
            acc[0][b] = fmaf(b0.z, xv.z, acc[0][b]);
            acc[0][b] = fmaf(b0.w, xv.w, acc[0][b]);
            acc[1][b] = fmaf(b1.x, xv.x, acc[1][b]);
            acc[1][b] = fmaf(b1.y, xv.y, acc[1][b]);
            acc[1][b] = fmaf(b1.z, xv.z, acc[1][b]);
            acc[1][b] = fmaf(b1.w, xv.w, acc[1][b]);
            acc[2][b] = fmaf(b2.x, xv.x, acc[2][b]);
            acc[2][b] = fmaf(b2.y, xv.y, acc[2][b]);
            acc[2][b] = fmaf(b2.z, xv.z, acc[2][b]);
            acc[2][b] = fmaf(b2.w, xv.w, acc[2][b]);
            acc[3][b] = fmaf(b3.x, xv.x, acc[3][b]);
            acc[3][b] = fmaf(b3.y, xv.y, acc[3][b]);
            acc[3][b] = fmaf(b3.z, xv.z, acc[3][b]);
            acc[3][b] = fmaf(b3.w, xv.w, acc[3][b]);
        }
    }

    // Intra-wave butterfly reduction of all 32 partials
    #pragma unroll
    for (int r = 0; r < 4; ++r)
        #pragma unroll
        for (int b = 0; b < BATCH; ++b)
            #pragma unroll
            for (int off = 32; off > 0; off >>= 1)
                acc[r][b] += __shfl_down(acc[r][b], off);

    __shared__ float red[4][32];
    const int wave = tid >> 6;
    const int lane = tid & 63;
    if (lane == 0) {
        #pragma unroll
        for (int r = 0; r < 4; ++r)
            #pragma unroll
            for (int b = 0; b < BATCH; ++b)
                red[wave][r * BATCH + b] = acc[r][b];
    }
    __syncthreads();

    if (tid < 32) {
        const int r = tid >> 3;   // row 0..3
        const int b = tid & 7;    // batch
        float v = red[0][tid] + red[1][tid] + red[2][tid] + red[3][tid];
        part[((size_t)blockIdx.y * NLR + rbase + r) * BATCH + b] = v;
    }
}

// ---------------------------------------------------------------------------
// Kernel B: partial-sum + rotation (staged in LDS) + reconstruction.
// grid = 400 blocks; block = 64 pixels x all 800 nlr, k-split across 4 waves.
// Direct stores, no atomics, no memset.
// ---------------------------------------------------------------------------
__global__ __launch_bounds__(256) void recon_kernel(
    const float* __restrict__ basis,   // [800][25600]
    const float* __restrict__ part,    // [KSPLIT][800][8]
    const float* __restrict__ angles,  // [8]
    float* __restrict__ out)           // [8][25600]
{
    __shared__ float rl[NLR * BATCH];          // 25.6 KB rotated coeffs
    __shared__ float red[RKS - 1][RPIX][BATCH]; // 6 KB reduce buffer
    __shared__ float cst[LDIM * BATCH], snt[LDIM * BATCH]; // 1.25 KB tables

    const int tid = threadIdx.x;

    // sin/cos table: 160 entries
    if (tid < LDIM * BATCH) {
        const int l = tid >> 3;
        const int b = tid & 7;
        __sincosf(angles[b] * (float)l, &snt[tid], &cst[tid]);
    }
    __syncthreads();

    // Stage: sum 5 partials, rotate.  a = c0*ca + c1*sa ; b = c1*ca - c0*sa
    for (int idx = tid; idx < NLR * BATCH; idx += 256) {
        const int nlr = idx >> 3;
        const int b   = idx & 7;
        float self = 0.0f, other = 0.0f;
        #pragma unroll
        for (int s = 0; s < KSPLIT; ++s) {
            self  += part[((size_t)s * NLR + nlr) * BATCH + b];
            other += part[((size_t)s * NLR + (nlr ^ 1)) * BATCH + b];
        }
        const int l  = (nlr >> 1) % LDIM;
        const float ca = cst[l * BATCH + b];
        const float sa = snt[l * BATCH + b];
        rl[idx] = (nlr & 1) == 0 ? fmaf(self, ca, other * sa)
                                 : fmaf(self, ca, -other * sa);
    }
    __syncthreads();

    const int lane = tid & 63;
    const int ks   = tid >> 6;                 // wave = k-slice
    const int pix  = blockIdx.x * RPIX + lane;

    float acc[BATCH];
    #pragma unroll
    for (int b = 0; b < BATCH; ++b) acc[b] = 0.0f;

    const float* __restrict__ bp = basis + (size_t)(ks * RKLEN) * PIX + pix;
    const float* __restrict__ rp = &rl[(ks * RKLEN) * BATCH];

    #pragma unroll 10
    for (int k = 0; k < RKLEN; ++k) {
        float bv = bp[(size_t)k * PIX];
        float4 v0 = *(const float4*)&rp[k * BATCH];
        float4 v1 = *(const float4*)&rp[k * BATCH + 4];
        acc[0] = fmaf(bv, v0.x, acc[0]);
        acc[1] = fmaf(bv, v0.y, acc[1]);
        acc[2] = fmaf(bv, v0.z, acc[2]);
        acc[3] = fmaf(bv, v0.w, acc[3]);
        acc[4] = fmaf(bv, v1.x, acc[4]);
        acc[5] = fmaf(bv, v1.y, acc[5]);
        acc[6] = fmaf(bv, v1.z, acc[6]);
        acc[7] = fmaf(bv, v1.w, acc[7]);
    }

    if (ks > 0) {
        #pragma unroll
        for (int b = 0; b < BATCH; ++b)
            red[ks - 1][lane][b] = acc[b];
    }
    __syncthreads();

    if (ks == 0) {
        #pragma unroll
        for (int w = 0; w < RKS - 1; ++w)
            #pragma unroll
            for (int b = 0; b < BATCH; ++b)
                acc[b] += red[w][lane][b];
        #pragma unroll
        for (int b = 0; b < BATCH; ++b)
            out[(size_t)b * PIX + pix] = acc[b];
    }
}

extern "C" void kernel_launch(void* const* d_in, const int* in_sizes, int n_in,
                              void* d_out, int out_size, void* d_ws, size_t ws_size,
                              hipStream_t stream) {
    (void)in_sizes; (void)n_in; (void)ws_size; (void)out_size;

    const float* x      = (const float*)d_in[0];   // [8][1][160][160]
    const float* basis  = (const float*)d_in[1];   // [20][20][2][160][160]
    const float* angles = (const float*)d_in[2];   // [8]
    float* out  = (float*)d_out;                   // [8][1][160][160]
    float* part = (float*)d_ws;                    // [5][800][8] = 128 KB

    proj_kernel<<<dim3(NLPAIRS / NLG, KSPLIT), dim3(256), 0, stream>>>(x, basis, part);
    recon_kernel<<<dim3(PIX / RPIX), dim3(256), 0, stream>>>(basis, part, angles, out);
}

// Round 4
// 41.762 us; speedup vs baseline: 1.3624x; 1.0087x over previous
//
#include <hip/hip_runtime.h>
#include <math.h>

// Problem constants
#define BATCH   8
#define LDIM    20
#define PIX     25600   // 160*160
#define PIX4    6400    // PIX/4 (float4 elements per image)
#define NLPAIRS 400     // N*L
#define NLR     800     // N*L*2

// Projection split
#define NLG     2                   // nl-pairs per block (4 basis rows)
#define KSPLIT  5                   // pixel-dimension split
#define SLICE   (PIX4 / KSPLIT)     // 1280 float4 = 5 iters * 256 threads

// Reconstruction split
#define RPIX    64                  // pixels per recon block
#define RKS     8                   // k-slices (one per wave, 512 threads)
#define RKLEN   (NLR / RKS)         // 100 k per wave

// ---------------------------------------------------------------------------
// Kernel A: split-K projection, no atomics.
// grid = (200 nl-groups, 5 K-slices). Each block handles 4 basis rows over a
// 1280-float4 pixel slice, reduces 32 partials, writes part[slice][800][8].
// ---------------------------------------------------------------------------
__global__ __launch_bounds__(256) void proj_kernel(
    const float* __restrict__ x,       // [8][25600]
    const float* __restrict__ basis,   // [800][25600]
    float* __restrict__ part)          // [KSPLIT][800][8]
{
    const int tid   = threadIdx.x;
    const int rbase = blockIdx.x * (NLG * 2);        // first basis row (4 rows)
    const int kbase = blockIdx.y * SLICE;            // float4 offset of slice

    const float4* __restrict__ r0 = (const float4*)(basis + (size_t)(rbase + 0) * PIX);
    const float4* __restrict__ r1 = (const float4*)(basis + (size_t)(rbase + 1) * PIX);
    const float4* __restrict__ r2 = (const float4*)(basis + (size_t)(rbase + 2) * PIX);
    const float4* __restrict__ r3 = (const float4*)(basis + (size_t)(rbase + 3) * PIX);
    const float4* __restrict__ x4 = (const float4*)x;

    float acc[4][BATCH];
    #pragma unroll
    for (int r = 0; r < 4; ++r)
        #pragma unroll
        for (int b = 0; b < BATCH; ++b) acc[r][b] = 0.0f;

    #pragma unroll
    for (int it = 0; it < SLICE / 256; ++it) {
        const int i = kbase + it * 256 + tid;
        float4 b0 = r0[i];
        float4 b1 = r1[i];
        float4 b2 = r2[i];
        float4 b3 = r3[i];
        #pragma unroll
        for (int b = 0; b < BATCH; ++b) {
            float4 xv = x4[(size_t)b * PIX4 + i];
            acc[0][b] = fmaf(b0.x, xv.x, acc[0][b]);
            acc[0][b] = fmaf(b0.y, xv.y, acc[0][b]);
            acc[0][b] = fmaf(b0.z, xv.z, acc[0][b]);
            acc[0][b] = fmaf(b0.w, xv.w, acc[0][b]);
            acc[1][b] = fmaf(b1.x, xv.x, acc[1][b]);
            acc[1][b] = fmaf(b1.y, xv.y, acc[1][b]);
            acc[1][b] = fmaf(b1.z, xv.z, acc[1][b]);
            acc[1][b] = fmaf(b1.w, xv.w, acc[1][b]);
            acc[2][b] = fmaf(b2.x, xv.x, acc[2][b]);
            acc[2][b] = fmaf(b2.y, xv.y, acc[2][b]);
            acc[2][b] = fmaf(b2.z, xv.z, acc[2][b]);
            acc[2][b] = fmaf(b2.w, xv.w, acc[2][b]);
            acc[3][b] = fmaf(b3.x, xv.x, acc[3][b]);
            acc[3][b] = fmaf(b3.y, xv.y, acc[3][b]);
            acc[3][b] = fmaf(b3.z, xv.z, acc[3][b]);
            acc[3][b] = fmaf(b3.w, xv.w, acc[3][b]);
        }
    }

    // Intra-wave butterfly reduction of all 32 partials
    #pragma unroll
    for (int r = 0; r < 4; ++r)
        #pragma unroll
        for (int b = 0; b < BATCH; ++b)
            #pragma unroll
            for (int off = 32; off > 0; off >>= 1)
                acc[r][b] += __shfl_down(acc[r][b], off);

    __shared__ float red[4][32];
    const int wave = tid >> 6;
    const int lane = tid & 63;
    if (lane == 0) {
        #pragma unroll
        for (int r = 0; r < 4; ++r)
            #pragma unroll
            for (int b = 0; b < BATCH; ++b)
                red[wave][r * BATCH + b] = acc[r][b];
    }
    __syncthreads();

    if (tid < 32) {
        const int r = tid >> 3;   // row 0..3
        const int b = tid & 7;    // batch
        float v = red[0][tid] + red[1][tid] + red[2][tid] + red[3][tid];
        part[((size_t)blockIdx.y * NLR + rbase + r) * BATCH + b] = v;
    }
}

// ---------------------------------------------------------------------------
// Kernel B: partial-sum + rotation, computed ONCE.
// grid = 25 blocks * 256 = 6400 threads = one per (nlr, b).
// ---------------------------------------------------------------------------
__global__ __launch_bounds__(256) void rotate_kernel(
    const float* __restrict__ part,    // [KSPLIT][800][8]
    const float* __restrict__ angles,  // [8]
    float* __restrict__ rot)           // [800][8]
{
    const int idx = blockIdx.x * 256 + threadIdx.x;   // 0..6399
    const int nlr = idx >> 3;
    const int b   = idx & 7;

    float self = 0.0f, other = 0.0f;
    #pragma unroll
    for (int s = 0; s < KSPLIT; ++s) {
        self  += part[((size_t)s * NLR + nlr) * BATCH + b];
        other += part[((size_t)s * NLR + (nlr ^ 1)) * BATCH + b];
    }
    const int l = (nlr >> 1) % LDIM;
    float ca, sa;
    __sincosf(angles[b] * (float)l, &sa, &ca);
    // a = c0*ca + c1*sa ; b = c1*ca - c0*sa
    rot[idx] = (nlr & 1) == 0 ? fmaf(self, ca, other * sa)
                              : fmaf(self, ca, -other * sa);
}

// ---------------------------------------------------------------------------
// Kernel C: reconstruction.
// grid = 400 blocks of 512 threads (8 waves). Each wave owns a 100-k slice
// over 64 pixels; LDS tree-reduce across waves; direct coalesced stores.
// ---------------------------------------------------------------------------
__global__ __launch_bounds__(512) void recon_kernel(
    const float* __restrict__ basis,   // [800][25600]
    const float* __restrict__ rot,     // [800][8]
    float* __restrict__ out)           // [8][25600]
{
    __shared__ float rl[NLR * BATCH];            // 25.6 KB rotated coeffs
    __shared__ float red[RKS - 1][BATCH][RPIX];  // 14.3 KB, lane-consecutive

    const int tid = threadIdx.x;

    // Stage rotated coeffs (simple L2 copy, broadcast-read later)
    for (int idx = tid; idx < NLR * BATCH; idx += 512)
        rl[idx] = rot[idx];
    __syncthreads();

    const int lane = tid & 63;
    const int ks   = tid >> 6;                 // wave = k-slice
    const int pix  = blockIdx.x * RPIX + lane;

    float acc[BATCH];
    #pragma unroll
    for (int b = 0; b < BATCH; ++b) acc[b] = 0.0f;

    const float* __restrict__ bp = basis + (size_t)(ks * RKLEN) * PIX + pix;
    const float* __restrict__ rp = &rl[(ks * RKLEN) * BATCH];

    #pragma unroll 10
    for (int k = 0; k < RKLEN; ++k) {
        float bv = bp[(size_t)k * PIX];
        float4 v0 = *(const float4*)&rp[k * BATCH];
        float4 v1 = *(const float4*)&rp[k * BATCH + 4];
        acc[0] = fmaf(bv, v0.x, acc[0]);
        acc[1] = fmaf(bv, v0.y, acc[1]);
        acc[2] = fmaf(bv, v0.z, acc[2]);
        acc[3] = fmaf(bv, v0.w, acc[3]);
        acc[4] = fmaf(bv, v1.x, acc[4]);
        acc[5] = fmaf(bv, v1.y, acc[5]);
        acc[6] = fmaf(bv, v1.z, acc[6]);
        acc[7] = fmaf(bv, v1.w, acc[7]);
    }

    if (ks > 0) {
        #pragma unroll
        for (int b = 0; b < BATCH; ++b)
            red[ks - 1][b][lane] = acc[b];   // consecutive lanes -> consecutive addrs
    }
    __syncthreads();

    if (ks == 0) {
        #pragma unroll
        for (int w = 0; w < RKS - 1; ++w)
            #pragma unroll
            for (int b = 0; b < BATCH; ++b)
                acc[b] += red[w][b][lane];
        #pragma unroll
        for (int b = 0; b < BATCH; ++b)
            out[(size_t)b * PIX + pix] = acc[b];
    }
}

extern "C" void kernel_launch(void* const* d_in, const int* in_sizes, int n_in,
                              void* d_out, int out_size, void* d_ws, size_t ws_size,
                              hipStream_t stream) {
    (void)in_sizes; (void)n_in; (void)ws_size; (void)out_size;

    const float* x      = (const float*)d_in[0];   // [8][1][160][160]
    const float* basis  = (const float*)d_in[1];   // [20][20][2][160][160]
    const float* angles = (const float*)d_in[2];   // [8]
    float* out  = (float*)d_out;                   // [8][1][160][160]
    float* part = (float*)d_ws;                    // [5][800][8] = 128 KB
    float* rot  = part + (size_t)KSPLIT * NLR * BATCH;  // [800][8] = 25.6 KB

    proj_kernel<<<dim3(NLPAIRS / NLG, KSPLIT), dim3(256), 0, stream>>>(x, basis, part);
    rotate_kernel<<<dim3(NLR * BATCH / 256), dim3(256), 0, stream>>>(part, angles, rot);
    recon_kernel<<<dim3(PIX / RPIX), dim3(512), 0, stream>>>(basis, rot, out);
}